// Round 4
// baseline (424.506 us; speedup 1.0000x reference)
//
#include <hip/hip_runtime.h>
#include <cmath>

#define BB 4
#define TT 8192
#define DD 1024
#define CL 256               // timesteps per chunk (= per block)
#define DBLK 64              // d's per block
#define NCH (TT/CL)          // 32 chunks per chain
#define NDB (DD/DBLK)        // 16 d-blocks
#define NCHAIN (BB*NDB)      // 64 chains
#define NBLK (NCHAIN*NCH)    // 2048 blocks
#define NPART 4              // waves per block = t-parts
#define PLEN (CL/NPART)      // 64 steps per part

typedef float fvec4 __attribute__((ext_vector_type(4)));
typedef unsigned long long u64;

// y[b,t,d] = Re(h[t]),  h[t] = r*h[t-1] + x[t],  r = exp(-|a_d|) * cis(w_d)
// Single fused kernel: chunk-local scan from LDS-resident x, publish chunk
// aggregate (agent-scope), full-walk Horner lookback over predecessor
// aggregates, apply with seed, write y. x is read from HBM exactly once.

__global__ __launch_bounds__(256, 2) void fftconv_fused(
    const float* __restrict__ x, const float* __restrict__ decay,
    const float* __restrict__ freq, float2* __restrict__ agg,
    unsigned* __restrict__ flags, float* __restrict__ y)
{
    __shared__ float tile[CL*DBLK];        // 64 KB
    __shared__ float2 Ssub[NPART][DBLK];   // 2 KB  sub-part aggregates
    __shared__ float2 eoff[NPART][DBLK];   // 2 KB  exclusive in-chunk offsets

    const int tid  = threadIdx.x;
    const int lane = tid & 63;
    const int part = tid >> 6;             // 0..3 (wave index = t-part)
    const int bid  = blockIdx.x;
    const int c     = bid & (NCH-1);       // chunk index (low bits: dispatch order!)
    const int chain = bid >> 5;            // NCH=32
    const int dblk  = chain & (NDB-1);
    const int b     = chain >> 4;          // NDB=16

    const int d = dblk*DBLK + lane;
    const size_t xoff = ((size_t)(b*TT + c*CL))*DD + (size_t)dblk*DBLK;

    // per-d constants
    const float a = fabsf(decay[d]);
    const float w = freq[d];
    float s, cc;
    float e = expf(-a); sincosf(w, &s, &cc);
    const float rr = e*cc, ri = e*s;                      // r
    e = expf(-a*(float)PLEN); sincosf(w*(float)PLEN, &s, &cc);
    const float Msr = e*cc, Msi = e*s;                    // r^64
    e = expf(-a*(float)CL); sincosf(w*(float)CL, &s, &cc);
    const float Mr = e*cc, Mi = e*s;                      // r^256
    e = expf(-a*(float)(PLEN*part)); sincosf(w*(float)(PLEN*part), &s, &cc);
    const float Mpr = e*cc, Mpi = e*s;                    // r^(64*part)

    // ---- stage x tile into LDS (coalesced fvec4; LDS lane-linear, no conflicts) ----
    {
        const float* xb = x + xoff;
#pragma unroll
        for (int k = 0; k < 16; ++k) {
            int t  = k*16 + (tid >> 4);
            int dq = (tid & 15) << 2;
            fvec4 v = *reinterpret_cast<const fvec4*>(xb + (size_t)t*DD + dq);
            *reinterpret_cast<fvec4*>(&tile[t*DBLK + dq]) = v;
        }
    }
    __syncthreads();

    // ---- sub-part local scan from zero state ----
    float hr = 0.f, hi = 0.f;
    {
        const int rowbase = part*PLEN;
#pragma unroll 8
        for (int t = 0; t < PLEN; ++t) {
            float xv = tile[(rowbase + t)*DBLK + lane];
            float nr = fmaf(rr, hr, fmaf(-ri, hi, xv));
            hi = fmaf(rr, hi, ri*hr);
            hr = nr;
        }
    }
    Ssub[part][lane] = make_float2(hr, hi);
    __syncthreads();

    // ---- stitch (wave 0): chunk aggregate + exclusive per-part offsets; publish A ----
    if (part == 0) {
        float er = 0.f, ei = 0.f;
#pragma unroll
        for (int p = 0; p < NPART; ++p) {
            eoff[p][lane] = make_float2(er, ei);
            float2 Sp = Ssub[p][lane];
            float nr = fmaf(Msr, er, fmaf(-Msi, ei, Sp.x));
            ei = fmaf(Msr, ei, fmaf(Msi, er, Sp.y));
            er = nr;
        }
        // er,ei == chunk aggregate A (state after CL steps from zero)
        float2 Av = make_float2(er, ei);
        u64 raw; __builtin_memcpy(&raw, &Av, 8);
        __hip_atomic_store(reinterpret_cast<u64*>(&agg[(size_t)bid*DBLK + lane]),
                           raw, __ATOMIC_RELAXED, __HIP_MEMORY_SCOPE_AGENT);
        __threadfence();
    }
    __syncthreads();
    if (tid == 0)
        __hip_atomic_store(&flags[bid], 1u, __ATOMIC_RELEASE, __HIP_MEMORY_SCOPE_AGENT);

    // ---- lookback: E = sum_{j<c} M^{c-1-j} * A_j  (Horner ascending, batched) ----
    float Er = 0.f, Ei = 0.f;
    {
        const int cbase = chain*NCH;       // == bid - c
        for (int j0 = 0; j0 < c; j0 += 8) {
            int jn = j0 + 8 < c ? j0 + 8 : c;
            if (tid == 0) {
                for (int j = j0; j < jn; ++j) {
                    while (__hip_atomic_load(&flags[cbase + j], __ATOMIC_ACQUIRE,
                                             __HIP_MEMORY_SCOPE_AGENT) == 0u) {
                        __builtin_amdgcn_s_sleep(2);
                    }
                }
            }
            __syncthreads();               // all payloads now published
            for (int j = j0; j < jn; ++j) {
                u64 raw = __hip_atomic_load(
                    reinterpret_cast<u64*>(&agg[(size_t)(cbase + j)*DBLK + lane]),
                    __ATOMIC_RELAXED, __HIP_MEMORY_SCOPE_AGENT);
                float2 A; __builtin_memcpy(&A, &raw, 8);
                float nr = fmaf(Mr, Er, fmaf(-Mi, Ei, A.x));
                Ei = fmaf(Mr, Ei, fmaf(Mi, Er, A.y));
                Er = nr;
            }
        }
    }

    // ---- apply: seed = eoff[part] + r^(64*part) * E; overwrite tile with Re(h) ----
    {
        float2 ev = eoff[part][lane];
        float sr = ev.x + (Mpr*Er - Mpi*Ei);
        float si = ev.y + (Mpr*Ei + Mpi*Er);
        const int rowbase = part*PLEN;
#pragma unroll 8
        for (int t = 0; t < PLEN; ++t) {
            int idx = (rowbase + t)*DBLK + lane;
            float xv = tile[idx];
            float nr = fmaf(rr, sr, fmaf(-ri, si, xv));
            si = fmaf(rr, si, ri*sr);
            sr = nr;
            tile[idx] = sr;                // consume-then-overwrite, same t
        }
    }
    __syncthreads();

    // ---- writeback: coalesced fvec4 nontemporal stores ----
    {
        float* yb = y + xoff;
#pragma unroll
        for (int k = 0; k < 16; ++k) {
            int t  = k*16 + (tid >> 4);
            int dq = (tid & 15) << 2;
            fvec4 v = *reinterpret_cast<const fvec4*>(&tile[t*DBLK + dq]);
            __builtin_nontemporal_store(v, reinterpret_cast<fvec4*>(yb + (size_t)t*DD + dq));
        }
    }
}

extern "C" void kernel_launch(void* const* d_in, const int* in_sizes, int n_in,
                              void* d_out, int out_size, void* d_ws, size_t ws_size,
                              hipStream_t stream) {
    const float* x     = (const float*)d_in[0];
    const float* decay = (const float*)d_in[1];
    const float* freq  = (const float*)d_in[2];
    float*       y     = (float*)d_out;

    float2*   agg   = (float2*)d_ws;                          // 2048*64*8 = 1 MB
    unsigned* flags = (unsigned*)((char*)d_ws + (size_t)NBLK*DBLK*sizeof(float2));

    // zero the lookback flags each launch (capture-legal async memset)
    hipMemsetAsync(flags, 0, NBLK*sizeof(unsigned), stream);
    fftconv_fused<<<NBLK, 256, 0, stream>>>(x, decay, freq, agg, flags, y);
}

// Round 6
// 182.376 us; speedup vs baseline: 2.3276x; 2.3276x over previous
//
#include <hip/hip_runtime.h>
#include <cmath>

#define BB 4
#define TT 8192
#define DD 1024
#define CL 256               // timesteps per chunk (= per block)
#define DBLK 64              // d's per block
#define NCH (TT/CL)          // 32 chunks per chain
#define NDB (DD/DBLK)        // 16 d-blocks
#define NCHAIN (BB*NDB)      // 64 chains
#define NBLK (NCHAIN*NCH)    // 2048 blocks
#define NPART 4              // waves per block = t-parts
#define PLEN (CL/NPART)      // 64 steps per part

typedef float fvec4 __attribute__((ext_vector_type(4)));
typedef unsigned long long u64;

// y[b,t,d] = Re(h[t]),  h[t] = r*h[t-1] + x[t],  r = exp(-|a_d|) * cis(w_d)
// Single fused kernel: chunk-local scan from LDS-resident x, publish chunk
// aggregate (agent-scope), full-walk Horner lookback over predecessor
// aggregates, apply with seed, write y. x is read from HBM exactly once.
//
// R4 lesson: agent-scope ACQUIRE loads emit a per-XCD L2 invalidate
// (buffer_inv sc1) on every poll -> invalidate storm -> 424 us. Poll
// RELAXED (sc1 loads are L3-coherent without invalidating), fence ONCE
// via __builtin_amdgcn_fence(acquire, "agent").

__global__ __launch_bounds__(256, 2) void fftconv_fused(
    const float* __restrict__ x, const float* __restrict__ decay,
    const float* __restrict__ freq, float2* __restrict__ agg,
    unsigned* __restrict__ flags, float* __restrict__ y)
{
    __shared__ float tile[CL*DBLK];        // 64 KB
    __shared__ float2 Ssub[NPART][DBLK];   // 2 KB  sub-part aggregates
    __shared__ float2 eoff[NPART][DBLK];   // 2 KB  exclusive in-chunk offsets
    __shared__ float2 Ebc[DBLK];           // 512 B broadcast of incoming state

    const int tid  = threadIdx.x;
    const int lane = tid & 63;
    const int part = tid >> 6;             // 0..3 (wave index = t-part)
    const int bid  = blockIdx.x;
    const int c     = bid & (NCH-1);       // chunk index (low bits: dispatch order!)
    const int chain = bid >> 5;            // NCH=32
    const int dblk  = chain & (NDB-1);
    const int b     = chain >> 4;          // NDB=16

    const int d = dblk*DBLK + lane;
    const size_t xoff = ((size_t)(b*TT + c*CL))*DD + (size_t)dblk*DBLK;

    // per-d constants
    const float a = fabsf(decay[d]);
    const float w = freq[d];
    float s, cc;
    float e = expf(-a); sincosf(w, &s, &cc);
    const float rr = e*cc, ri = e*s;                      // r
    e = expf(-a*(float)PLEN); sincosf(w*(float)PLEN, &s, &cc);
    const float Msr = e*cc, Msi = e*s;                    // r^64
    e = expf(-a*(float)CL); sincosf(w*(float)CL, &s, &cc);
    const float Mr = e*cc, Mi = e*s;                      // r^256
    e = expf(-a*(float)(PLEN*part)); sincosf(w*(float)(PLEN*part), &s, &cc);
    const float Mpr = e*cc, Mpi = e*s;                    // r^(64*part)

    // ---- stage x tile into LDS (coalesced fvec4; LDS lane-linear, no conflicts) ----
    {
        const float* xb = x + xoff;
#pragma unroll
        for (int k = 0; k < 16; ++k) {
            int t  = k*16 + (tid >> 4);
            int dq = (tid & 15) << 2;
            fvec4 v = *reinterpret_cast<const fvec4*>(xb + (size_t)t*DD + dq);
            *reinterpret_cast<fvec4*>(&tile[t*DBLK + dq]) = v;
        }
    }
    __syncthreads();

    // ---- sub-part local scan from zero state ----
    float hr = 0.f, hi = 0.f;
    {
        const int rowbase = part*PLEN;
#pragma unroll 8
        for (int t = 0; t < PLEN; ++t) {
            float xv = tile[(rowbase + t)*DBLK + lane];
            float nr = fmaf(rr, hr, fmaf(-ri, hi, xv));
            hi = fmaf(rr, hi, ri*hr);
            hr = nr;
        }
    }
    Ssub[part][lane] = make_float2(hr, hi);
    __syncthreads();

    // ---- stitch (wave 0): chunk aggregate + exclusive per-part offsets; publish A ----
    if (part == 0) {
        float er = 0.f, ei = 0.f;
#pragma unroll
        for (int p = 0; p < NPART; ++p) {
            eoff[p][lane] = make_float2(er, ei);
            float2 Sp = Ssub[p][lane];
            float nr = fmaf(Msr, er, fmaf(-Msi, ei, Sp.x));
            ei = fmaf(Msr, ei, fmaf(Msi, er, Sp.y));
            er = nr;
        }
        // er,ei == chunk aggregate A (state after CL steps from zero)
        float2 Av = make_float2(er, ei);
        u64 raw; __builtin_memcpy(&raw, &Av, 8);
        __hip_atomic_store(reinterpret_cast<u64*>(&agg[(size_t)bid*DBLK + lane]),
                           raw, __ATOMIC_RELAXED, __HIP_MEMORY_SCOPE_AGENT);
        __threadfence();                   // drain wave 0's payload stores
    }
    __syncthreads();
    if (tid == 0)
        __hip_atomic_store(&flags[bid], 1u, __ATOMIC_RELEASE, __HIP_MEMORY_SCOPE_AGENT);

    // ---- lookback (wave 0 only): E = sum_{j<c} M^{c-1-j} * A_j ----
    if (part == 0) {
        const int cbase = chain*NCH;       // == bid - c

        // lane-parallel poll: lane j watches flag j. RELAXED = no L2 invalidate.
        if (lane < c) {
            while (__hip_atomic_load(&flags[cbase + lane], __ATOMIC_RELAXED,
                                     __HIP_MEMORY_SCOPE_AGENT) == 0u) {
                __builtin_amdgcn_s_sleep(1);
            }
        }
        if (c > 0)  // ONE acquire fence for the whole walk
            __builtin_amdgcn_fence(__ATOMIC_ACQUIRE, "agent");

        float Er = 0.f, Ei = 0.f;
        int j = 0;
        while (j + 8 <= c) {               // batches of 8: overlap L3 latency
            u64 q[8];
#pragma unroll
            for (int k = 0; k < 8; ++k)
                q[k] = __hip_atomic_load(
                    reinterpret_cast<u64*>(&agg[(size_t)(cbase + j + k)*DBLK + lane]),
                    __ATOMIC_RELAXED, __HIP_MEMORY_SCOPE_AGENT);
#pragma unroll
            for (int k = 0; k < 8; ++k) {
                float2 A; __builtin_memcpy(&A, &q[k], 8);
                float nr = fmaf(Mr, Er, fmaf(-Mi, Ei, A.x));
                Ei = fmaf(Mr, Ei, fmaf(Mi, Er, A.y));
                Er = nr;
            }
            j += 8;
        }
        for (; j < c; ++j) {
            u64 raw = __hip_atomic_load(
                reinterpret_cast<u64*>(&agg[(size_t)(cbase + j)*DBLK + lane]),
                __ATOMIC_RELAXED, __HIP_MEMORY_SCOPE_AGENT);
            float2 A; __builtin_memcpy(&A, &raw, 8);
            float nr = fmaf(Mr, Er, fmaf(-Mi, Ei, A.x));
            Ei = fmaf(Mr, Ei, fmaf(Mi, Er, A.y));
            Er = nr;
        }
        Ebc[lane] = make_float2(Er, Ei);
    }
    __syncthreads();

    // ---- apply: seed = eoff[part] + r^(64*part) * E; overwrite tile with Re(h) ----
    {
        float2 Ev = Ebc[lane];
        float2 ev = eoff[part][lane];
        float sr = ev.x + (Mpr*Ev.x - Mpi*Ev.y);
        float si = ev.y + (Mpr*Ev.y + Mpi*Ev.x);
        const int rowbase = part*PLEN;
#pragma unroll 8
        for (int t = 0; t < PLEN; ++t) {
            int idx = (rowbase + t)*DBLK + lane;
            float xv = tile[idx];
            float nr = fmaf(rr, sr, fmaf(-ri, si, xv));
            si = fmaf(rr, si, ri*sr);
            sr = nr;
            tile[idx] = sr;                // consume-then-overwrite, same t
        }
    }
    __syncthreads();

    // ---- writeback: coalesced fvec4 nontemporal stores ----
    {
        float* yb = y + xoff;
#pragma unroll
        for (int k = 0; k < 16; ++k) {
            int t  = k*16 + (tid >> 4);
            int dq = (tid & 15) << 2;
            fvec4 v = *reinterpret_cast<const fvec4*>(&tile[t*DBLK + dq]);
            __builtin_nontemporal_store(v, reinterpret_cast<fvec4*>(yb + (size_t)t*DD + dq));
        }
    }
}

extern "C" void kernel_launch(void* const* d_in, const int* in_sizes, int n_in,
                              void* d_out, int out_size, void* d_ws, size_t ws_size,
                              hipStream_t stream) {
    const float* x     = (const float*)d_in[0];
    const float* decay = (const float*)d_in[1];
    const float* freq  = (const float*)d_in[2];
    float*       y     = (float*)d_out;

    float2*   agg   = (float2*)d_ws;                          // 2048*64*8 = 1 MB
    unsigned* flags = (unsigned*)((char*)d_ws + (size_t)NBLK*DBLK*sizeof(float2));

    // zero the lookback flags each launch (capture-legal async memset)
    (void)hipMemsetAsync(flags, 0, NBLK*sizeof(unsigned), stream);
    fftconv_fused<<<NBLK, 256, 0, stream>>>(x, decay, freq, agg, flags, y);
}

// Round 7
// 70.130 us; speedup vs baseline: 6.0531x; 2.6005x over previous
//
#include <hip/hip_runtime.h>
#include <cmath>

#define BB 4
#define TT 8192
#define DD 1024
#define CL 256               // timesteps per chunk (= per block)
#define DBLK 64              // d's per block
#define NCH (TT/CL)          // 32 chunks per chain
#define NDB (DD/DBLK)        // 16 d-blocks
#define NCHAIN (BB*NDB)      // 64 chains
#define NBLK (NCHAIN*NCH)    // 2048 blocks
#define NPART 4              // waves per block = t-parts
#define PLEN (CL/NPART)      // 64 steps per part

typedef float fvec4 __attribute__((ext_vector_type(4)));
typedef unsigned long long u64;

// y[b,t,d] = Re(h[t]),  h[t] = r*h[t-1] + x[t],  r = exp(-|a_d|) * cis(w_d)
// Fused chunked-scan with FENCE-FREE decoupled lookback:
//   R4 lesson: per-poll ACQUIRE  -> buffer_inv storm      -> 424 us
//   R6 lesson: per-block wb/inv  (threadfence + release + one acquire)
//              still poisons every XCD L2                 -> 182 us
//   Fix: ALL cross-block traffic uses RELAXED agent-scope atomics (sc1,
//   L2-bypassing, L3-coherent). Ordering payload-before-flag is done with a
//   wave-local s_waitcnt vmcnt(0). Zero cache-maintenance ops in the kernel.

__global__ __launch_bounds__(256, 2) void fftconv_fused(
    const float* __restrict__ x, const float* __restrict__ decay,
    const float* __restrict__ freq, float2* __restrict__ agg,
    unsigned* __restrict__ flags, float* __restrict__ y)
{
    __shared__ float tile[CL*DBLK];        // 64 KB
    __shared__ float2 Ssub[NPART][DBLK];   // 2 KB  sub-part aggregates
    __shared__ float2 eoff[NPART][DBLK];   // 2 KB  exclusive in-chunk offsets
    __shared__ float2 Ebc[DBLK];           // 512 B broadcast of incoming state

    const int tid  = threadIdx.x;
    const int lane = tid & 63;
    const int part = tid >> 6;             // 0..3 (wave index = t-part)
    const int bid  = blockIdx.x;
    const int c     = bid & (NCH-1);       // chunk index (low bits: dispatch order!)
    const int chain = bid >> 5;            // NCH=32
    const int dblk  = chain & (NDB-1);
    const int b     = chain >> 4;          // NDB=16

    const int d = dblk*DBLK + lane;
    const size_t xoff = ((size_t)(b*TT + c*CL))*DD + (size_t)dblk*DBLK;

    // per-d constants
    const float a = fabsf(decay[d]);
    const float w = freq[d];
    float s, cc;
    float e = expf(-a); sincosf(w, &s, &cc);
    const float rr = e*cc, ri = e*s;                      // r
    e = expf(-a*(float)PLEN); sincosf(w*(float)PLEN, &s, &cc);
    const float Msr = e*cc, Msi = e*s;                    // r^64
    e = expf(-a*(float)CL); sincosf(w*(float)CL, &s, &cc);
    const float Mr = e*cc, Mi = e*s;                      // r^256
    e = expf(-a*(float)(PLEN*part)); sincosf(w*(float)(PLEN*part), &s, &cc);
    const float Mpr = e*cc, Mpi = e*s;                    // r^(64*part)

    // ---- stage x tile into LDS (coalesced fvec4; LDS lane-linear, no conflicts) ----
    {
        const float* xb = x + xoff;
#pragma unroll
        for (int k = 0; k < 16; ++k) {
            int t  = k*16 + (tid >> 4);
            int dq = (tid & 15) << 2;
            fvec4 v = *reinterpret_cast<const fvec4*>(xb + (size_t)t*DD + dq);
            *reinterpret_cast<fvec4*>(&tile[t*DBLK + dq]) = v;
        }
    }
    __syncthreads();

    // ---- sub-part local scan from zero state ----
    float hr = 0.f, hi = 0.f;
    {
        const int rowbase = part*PLEN;
#pragma unroll 8
        for (int t = 0; t < PLEN; ++t) {
            float xv = tile[(rowbase + t)*DBLK + lane];
            float nr = fmaf(rr, hr, fmaf(-ri, hi, xv));
            hi = fmaf(rr, hi, ri*hr);
            hr = nr;
        }
    }
    Ssub[part][lane] = make_float2(hr, hi);
    __syncthreads();

    // ---- wave 0: stitch parts, publish aggregate + flag, then lookback ----
    if (part == 0) {
        float er = 0.f, ei = 0.f;
#pragma unroll
        for (int p = 0; p < NPART; ++p) {
            eoff[p][lane] = make_float2(er, ei);
            float2 Sp = Ssub[p][lane];
            float nr = fmaf(Msr, er, fmaf(-Msi, ei, Sp.x));
            ei = fmaf(Msr, ei, fmaf(Msi, er, Sp.y));
            er = nr;
        }
        // er,ei == chunk aggregate A (state after CL steps from zero)
        float2 Av = make_float2(er, ei);
        u64 raw; __builtin_memcpy(&raw, &Av, 8);
        __hip_atomic_store(reinterpret_cast<u64*>(&agg[(size_t)bid*DBLK + lane]),
                           raw, __ATOMIC_RELAXED, __HIP_MEMORY_SCOPE_AGENT);
        // order payload (L3) before flag (L3): drain this wave's stores only.
        asm volatile("s_waitcnt vmcnt(0)" ::: "memory");
        if (lane == 0)
            __hip_atomic_store(&flags[bid], 1u, __ATOMIC_RELAXED,
                               __HIP_MEMORY_SCOPE_AGENT);

        // ---- lookback: E = sum_{j<c} M^{c-1-j} * A_j (all sc1, no fences) ----
        const int cbase = chain*NCH;       // == bid - c

        // lane-parallel poll: lane j watches flag j.
        if (lane < c) {
            while (__hip_atomic_load(&flags[cbase + lane], __ATOMIC_RELAXED,
                                     __HIP_MEMORY_SCOPE_AGENT) == 0u) {
                __builtin_amdgcn_s_sleep(1);
            }
        }
        asm volatile("" ::: "memory");     // keep payload loads below the poll

        float Er = 0.f, Ei = 0.f;
        int j = 0;
        while (j + 8 <= c) {               // batches of 8: overlap L3 latency
            u64 q[8];
#pragma unroll
            for (int k = 0; k < 8; ++k)
                q[k] = __hip_atomic_load(
                    reinterpret_cast<u64*>(&agg[(size_t)(cbase + j + k)*DBLK + lane]),
                    __ATOMIC_RELAXED, __HIP_MEMORY_SCOPE_AGENT);
#pragma unroll
            for (int k = 0; k < 8; ++k) {
                float2 A; __builtin_memcpy(&A, &q[k], 8);
                float nr = fmaf(Mr, Er, fmaf(-Mi, Ei, A.x));
                Ei = fmaf(Mr, Ei, fmaf(Mi, Er, A.y));
                Er = nr;
            }
            j += 8;
        }
        for (; j < c; ++j) {
            u64 raw2 = __hip_atomic_load(
                reinterpret_cast<u64*>(&agg[(size_t)(cbase + j)*DBLK + lane]),
                __ATOMIC_RELAXED, __HIP_MEMORY_SCOPE_AGENT);
            float2 A; __builtin_memcpy(&A, &raw2, 8);
            float nr = fmaf(Mr, Er, fmaf(-Mi, Ei, A.x));
            Ei = fmaf(Mr, Ei, fmaf(Mi, Er, A.y));
            Er = nr;
        }
        Ebc[lane] = make_float2(Er, Ei);
    }
    __syncthreads();

    // ---- apply: seed = eoff[part] + r^(64*part) * E; overwrite tile with Re(h) ----
    {
        float2 Ev = Ebc[lane];
        float2 ev = eoff[part][lane];
        float sr = ev.x + (Mpr*Ev.x - Mpi*Ev.y);
        float si = ev.y + (Mpr*Ev.y + Mpi*Ev.x);
        const int rowbase = part*PLEN;
#pragma unroll 8
        for (int t = 0; t < PLEN; ++t) {
            int idx = (rowbase + t)*DBLK + lane;
            float xv = tile[idx];
            float nr = fmaf(rr, sr, fmaf(-ri, si, xv));
            si = fmaf(rr, si, ri*sr);
            sr = nr;
            tile[idx] = sr;                // consume-then-overwrite, same t
        }
    }
    __syncthreads();

    // ---- writeback: coalesced fvec4 nontemporal stores ----
    {
        float* yb = y + xoff;
#pragma unroll
        for (int k = 0; k < 16; ++k) {
            int t  = k*16 + (tid >> 4);
            int dq = (tid & 15) << 2;
            fvec4 v = *reinterpret_cast<const fvec4*>(&tile[t*DBLK + dq]);
            __builtin_nontemporal_store(v, reinterpret_cast<fvec4*>(yb + (size_t)t*DD + dq));
        }
    }
}

extern "C" void kernel_launch(void* const* d_in, const int* in_sizes, int n_in,
                              void* d_out, int out_size, void* d_ws, size_t ws_size,
                              hipStream_t stream) {
    const float* x     = (const float*)d_in[0];
    const float* decay = (const float*)d_in[1];
    const float* freq  = (const float*)d_in[2];
    float*       y     = (float*)d_out;

    float2*   agg   = (float2*)d_ws;                          // 2048*64*8 = 1 MB
    unsigned* flags = (unsigned*)((char*)d_ws + (size_t)NBLK*DBLK*sizeof(float2));

    // zero the lookback flags each launch (capture-legal async memset);
    // kernel-boundary implicit release flushes these zeros to L3 before the
    // kernel's sc1 reads can observe them.
    (void)hipMemsetAsync(flags, 0, NBLK*sizeof(unsigned), stream);
    fftconv_fused<<<NBLK, 256, 0, stream>>>(x, decay, freq, agg, flags, y);
}